// Round 1
// 690.873 us; speedup vs baseline: 1.0605x; 1.0605x over previous
//
#include <hip/hip_runtime.h>
#include <stdint.h>
#include <stddef.h>

// CNNLSTM: embed -> conv1d(K=5) -> ReLU -> maxpool4 -> LSTM(T=1023,H=128) -> fc(2)
// Inputs: x int32; all float tensors float32. Output f32.
// Internals: bf16 MFMA for conv + input-projection GEMMs; f16 dot2 recurrence.

typedef __bf16 bf16;
typedef __bf16 bf16x8 __attribute__((ext_vector_type(8)));
typedef float  f32x4  __attribute__((ext_vector_type(4)));
typedef _Float16 f16;
typedef f16 f16x2 __attribute__((ext_vector_type(2)));
typedef f16 f16x4 __attribute__((ext_vector_type(4)));
typedef f16 f16x8 __attribute__((ext_vector_type(8)));

#define MFMA16(a, b, c) __builtin_amdgcn_mfma_f32_16x16x32_bf16((a), (b), (c), 0, 0, 0)

#if __has_builtin(__builtin_amdgcn_fdot2)
#define DOT2(a, b, c) __builtin_amdgcn_fdot2((a), (b), (c), false)
#else
#define DOT2(a, b, c) ((c) + (float)(a).x * (float)(b).x + (float)(a).y * (float)(b).y)
#endif

// Barrier draining LDS (lgkm) but NOT in-flight global prefetch loads.
#define LGKM_BARRIER() asm volatile("s_waitcnt lgkmcnt(0)\ns_barrier" ::: "memory")

// ---------------- ws layout (bytes) ----------------
#define WS_BT     0               // conv weights repacked [64][640] bf16 =    81,920
#define WS_WIHB   81920           // w_ih bf16 [512][64]                  =    65,536
#define WS_POOLED 278528          // pooled bf16 [64][1024][64]           = 8,388,608
#define WS_EMB    8667136         // emb bf16 [20000][128]                = 5,120,000
#define WS_XG     8667136         // xgc f16 [64][128][128][4][8]         = 67,108,864
// (xgc overlaps emb_bf16: emb dead after conv_pool)

// ============ prep A: emb f32 -> bf16 ============
__global__ void emb_cvt_k(const float* __restrict__ emb, bf16* __restrict__ embb) {
    int g = blockIdx.x * 256 + threadIdx.x;
    f32x4 v = *(const f32x4*)(emb + g * 4);
    bf16* d = embb + g * 4;
    d[0] = (bf16)v[0]; d[1] = (bf16)v[1]; d[2] = (bf16)v[2]; d[3] = (bf16)v[3];
}

// ============ prep B: conv_w repack->bf16; w_ih->bf16 ============
__global__ void prep_small_k(const float* __restrict__ conv_w, bf16* __restrict__ bt,
                             const float* __restrict__ w_ih, bf16* __restrict__ w_ihb) {
    int g = blockIdx.x * 256 + threadIdx.x;
    if (g < 64 * 640) {
        int f = g / 640, kk = g - f * 640;
        int k = kk >> 7, e = kk & 127;
        bt[g] = (bf16)conv_w[(f * 128 + e) * 5 + k];
    } else {
        int h = g - 64 * 640;
        if (h < 512 * 64) w_ihb[h] = (bf16)w_ih[h];
    }
}

// ============ kernel 1: embed-gather + conv + ReLU + pool4 ============
__global__ __launch_bounds__(256, 2) void conv_pool_k(
    const int* __restrict__ x, const bf16* __restrict__ embb,
    const bf16* __restrict__ bt, const float* __restrict__ conv_b,
    bf16* __restrict__ pooled)
{
    __shared__ bf16 T[144 * 136];  // 136 = 128 + 8 pad
    const int b   = blockIdx.x >> 5;
    const int l0  = (blockIdx.x & 31) << 7;
    const int tid = threadIdx.x;
    const int ln  = tid & 63, w = tid >> 6;
    const int l15 = ln & 15, quad = ln >> 4;
    const int f   = w * 16 + l15;

    bf16x8 bfrag[20];
    #pragma unroll
    for (int kc = 0; kc < 20; ++kc) {
        uint4 v = *(const uint4*)(bt + f * 640 + kc * 32 + quad * 8);
        bfrag[kc] = __builtin_bit_cast(bf16x8, v);
    }
    const float cb = conv_b[f];

    #pragma unroll
    for (int p = 0; p < 9; ++p) {
        int r = p * 16 + (tid >> 4);
        int cg = tid & 15;
        int token = l0 + r; if (token > 4095) token = 4095;
        int idx = x[b * 4096 + token];
        uint4 v = *(const uint4*)(embb + idx * 128 + cg * 8);
        *(uint4*)(&T[r * 136 + cg * 8]) = v;
    }
    __syncthreads();

    f32x4 acc[8];
    #pragma unroll
    for (int tm = 0; tm < 8; ++tm) acc[tm] = (f32x4){0.f, 0.f, 0.f, 0.f};

    #pragma unroll
    for (int kc = 0; kc < 20; ++kc) {
        const int ktap = kc >> 2;
        const int ecol = (kc & 3) * 32 + quad * 8;
        #pragma unroll
        for (int tm = 0; tm < 8; ++tm) {
            int row = tm * 16 + l15 + ktap;
            bf16x8 a = *(const bf16x8*)(&T[row * 136 + ecol]);
            acc[tm] = MFMA16(a, bfrag[kc], acc[tm]);
        }
    }

    #pragma unroll
    for (int tm = 0; tm < 8; ++tm) {
        float mx = fmaxf(fmaxf(acc[tm][0], acc[tm][1]), fmaxf(acc[tm][2], acc[tm][3]));
        mx = fmaxf(mx + cb, 0.f);
        int t = (l0 >> 2) + tm * 4 + quad;
        if (t < 1023) pooled[(b * 1024 + t) * 64 + f] = (bf16)mx;
    }
}

// ============ kernel 2: xgc = pooled @ w_ih^T + (b_ih+b_hh), chunk-layout f16 ============
// xgc[b][c][unit][gate][j], t = c*8+j. LSTM thread reads 64 contiguous B/chunk.
__global__ __launch_bounds__(256, 2) void xg_gemm_k(
    const bf16* __restrict__ pooled, const bf16* __restrict__ w_ihb,
    const float* __restrict__ b_ih, const float* __restrict__ b_hh,
    f16* __restrict__ xg)
{
    __shared__ bf16 A[256 * 72];  // 72 = 64 + 8 pad
    const int m0  = blockIdx.x * 256;
    const int tid = threadIdx.x;
    const int ln  = tid & 63, w = tid >> 6;
    const int l15 = ln & 15, quad = ln >> 4;

    #pragma unroll
    for (int i = 0; i < 8; ++i) {
        int task = i * 256 + tid;
        int row = task >> 3, ch = task & 7;
        uint4 v = *(const uint4*)(pooled + (m0 + row) * 64 + ch * 8);
        *(uint4*)(&A[row * 72 + ch * 8]) = v;
    }
    __syncthreads();

    bf16x8 afrag[4][2];
    #pragma unroll
    for (int mt = 0; mt < 4; ++mt)
        #pragma unroll
        for (int kc = 0; kc < 2; ++kc)
            afrag[mt][kc] = *(const bf16x8*)(&A[((w * 4 + mt) * 16 + l15) * 72 + kc * 32 + quad * 8]);

    const int b_idx = m0 >> 10;
    const int tbase = m0 & 1023;

    for (int nt = 0; nt < 32; ++nt) {
        const int nn = nt * 16 + l15;
        uint4 v0 = *(const uint4*)(w_ihb + nn * 64 + quad * 8);
        uint4 v1 = *(const uint4*)(w_ihb + nn * 64 + 32 + quad * 8);
        bf16x8 bf0 = __builtin_bit_cast(bf16x8, v0);
        bf16x8 bf1 = __builtin_bit_cast(bf16x8, v1);
        const float bias = b_ih[nn] + b_hh[nn];
        const int unit = nn & 127, gate = nn >> 7;
        #pragma unroll
        for (int mt = 0; mt < 4; ++mt) {
            f32x4 acc = (f32x4){0.f, 0.f, 0.f, 0.f};
            acc = MFMA16(afrag[mt][0], bf0, acc);
            acc = MFMA16(afrag[mt][1], bf1, acc);
            int t0 = tbase + (w * 4 + mt) * 16 + quad * 4;   // t0 % 4 == 0
            f16x4 sv = {(f16)(acc[0] + bias), (f16)(acc[1] + bias),
                        (f16)(acc[2] + bias), (f16)(acc[3] + bias)};
            size_t off = (((size_t)(b_idx * 128 + (t0 >> 3)) * 128 + unit) * 4 + gate) * 8 + (t0 & 7);
            *(f16x4*)(xg + off) = sv;   // 8B store, (t0&7) in {0,4}
        }
    }
}

// ============ kernel 3: LSTM recurrence + fc head ============
// 64 WGs x 512 threads (8 waves = 2 waves/EU on 64 of 256 CUs).
// Quad of threads (4u..4u+3) owns unit u: sub = t&3 -> gate-pair gp = sub>>1
// ({i,f} or {g,o}) x K-half kh = sub&1. Per-thread weights: 2 gates x 64 K
// = 64 f16x2 VGPRs (total live ~110 regs -> NO spill at any allocator cap;
// previous 256-thread version needed ~190 live with VGPR_Count=128 -> per-step
// spill traffic was ~400 extra VALU cyc/step).
// All cross-lane traffic is intra-quad -> DPP quad_perm (VALU speed), no DS
// shuffles. Activations run in parallel on both kh==0... (all) lanes via the
// unified form  act(v) = alpha + beta * rcp(1 + exp2(gamma*v))
// (sigmoid: a=0,b=1,g=-log2e; tanh: a=1,b=-2,g=+2log2e), constants per-thread.
// h double-buffered in LDS -> one lgkm barrier/step; xq prefetch via vmcnt
// stays in flight across the barrier.
__device__ inline float dpp_xor1(float v) {   // quad_perm [1,0,3,2]
    return __builtin_bit_cast(float,
        __builtin_amdgcn_update_dpp(0, __builtin_bit_cast(int, v), 177, 0xf, 0xf, true));
}
__device__ inline float dpp_xor2(float v) {   // quad_perm [2,3,0,1]
    return __builtin_bit_cast(float,
        __builtin_amdgcn_update_dpp(0, __builtin_bit_cast(int, v), 78, 0xf, 0xf, true));
}
__device__ inline float act_(float v, float gml2, float alpha, float beta) {
    v = fminf(fmaxf(v, -30.f), 30.f);
    return alpha + beta * __builtin_amdgcn_rcpf(1.f + __builtin_amdgcn_exp2f(gml2 * v));
}
__device__ inline float tanh_(float v) {
    v = fminf(fmaxf(v, -30.f), 30.f);
    return 1.f - 2.f * __builtin_amdgcn_rcpf(1.f + __builtin_amdgcn_exp2f(2.8853901817779268f * v));
}

__global__ __launch_bounds__(512, 2) __attribute__((amdgpu_waves_per_eu(2, 2)))
void lstm_fc_k(
    const f16* __restrict__ xgc, const float* __restrict__ w_hh,
    const float* __restrict__ fc_w, const float* __restrict__ fc_b,
    float* __restrict__ out)
{
    __shared__ __align__(16) f16 hp[2][128];
    const int b   = blockIdx.x;
    const int t   = threadIdx.x;   // 0..511
    const int u   = t >> 2;        // unit 0..127
    const int sub = t & 3;
    const int kh  = sub & 1;       // K-half
    const int gp  = sub >> 1;      // 0 -> gates {i,f}, 1 -> gates {g,o}
    const int g0  = gp * 2;

    // activation constants: A0 is sigm (gate i) or tanh (gate g); A1 always sigm
    const float gml2  = gp ? 2.8853901817779268f : -1.4426950408889634f;
    const float alpha = gp ? 1.f : 0.f;
    const float beta  = gp ? -2.f : 1.f;

    // weights: 2 gates x 64 K = 128 f16 = 64 f16x2 VGPRs
    f16x2 wv[2][32];
    #pragma unroll
    for (int gi = 0; gi < 2; ++gi) {
        const float* wr = w_hh + ((g0 + gi) * 128 + u) * 128 + kh * 64;
        #pragma unroll
        for (int c = 0; c < 16; ++c) {
            f32x4 v = *(const f32x4*)(wr + c * 4);
            wv[gi][c * 2 + 0] = (f16x2){(f16)v[0], (f16)v[1]};
            wv[gi][c * 2 + 1] = (f16x2){(f16)v[2], (f16)v[3]};
        }
    }
    #pragma unroll
    for (int gi = 0; gi < 2; ++gi)
        #pragma unroll
        for (int i = 0; i < 32; ++i) {
            uint32_t r = __builtin_bit_cast(uint32_t, wv[gi][i]);
            asm volatile("" : "+v"(r));           // pin: not remat-able
            wv[gi][i] = __builtin_bit_cast(f16x2, r);
        }

    // xq for this thread's 2 gates: xgc[b][c][u][g0..g0+1][0..7]
    const f16* xb = xgc + (size_t)b * 524288 + (size_t)u * 32 + (size_t)g0 * 8;
    f16x8 xq0, xq1, nxq0, nxq1;
    xq0 = *(const f16x8*)(xb);
    xq1 = *(const f16x8*)(xb + 8);

    if (t < 128) hp[0][t] = (f16)0.f;
    float cst = 0.f;
    int p = 0;
    LGKM_BARRIER();

    auto step = [&](int j) {
        const f16* hsrc = &hp[p][kh * 64];
        float a00 = 0.f, a01 = 0.f, a10 = 0.f, a11 = 0.f;
        #pragma unroll
        for (int c = 0; c < 8; ++c) {
            f16x8 h8 = *(const f16x8*)(hsrc + c * 8);   // 2-addr broadcast read
            f16x2 p0 = {h8[0], h8[1]}, p1 = {h8[2], h8[3]};
            f16x2 p2 = {h8[4], h8[5]}, p3 = {h8[6], h8[7]};
            a00 = DOT2(wv[0][c*4+0], p0, a00); a01 = DOT2(wv[0][c*4+1], p1, a01);
            a00 = DOT2(wv[0][c*4+2], p2, a00); a01 = DOT2(wv[0][c*4+3], p3, a01);
            a10 = DOT2(wv[1][c*4+0], p0, a10); a11 = DOT2(wv[1][c*4+1], p1, a11);
            a10 = DOT2(wv[1][c*4+2], p2, a10); a11 = DOT2(wv[1][c*4+3], p3, a11);
        }
        float a0 = a00 + a01, a1 = a10 + a11;
        a0 += dpp_xor1(a0);            // merge K-halves (intra-quad, VALU)
        a1 += dpp_xor1(a1);
        // activations in all lanes (a0/a1 complete everywhere after xor merge)
        float A0 = act_(a0 + (float)xq0[j], gml2, alpha, beta);
        float A1 = act_(a1 + (float)xq1[j], -1.4426950408889634f, 0.f, 1.f);
        // exchange gate pairs: sub0 gets (Ag, Ao) from sub2
        float rg = dpp_xor2(A0);
        float ro = dpp_xor2(A1);
        if (sub == 0) {                // A0=i, A1=f, rg=g, ro=o
            cst = A1 * cst + A0 * rg;
            hp[p ^ 1][u] = (f16)(ro * tanh_(cst));
        }
        p ^= 1;
        LGKM_BARRIER();
    };

    for (int c = 0; c < 127; ++c) {
        // prefetch next chunk (vmcnt: not drained by the lgkm barrier)
        nxq0 = *(const f16x8*)(xb + (size_t)(c + 1) * 4096);
        nxq1 = *(const f16x8*)(xb + (size_t)(c + 1) * 4096 + 8);
        #pragma unroll
        for (int j = 0; j < 8; ++j) step(j);
        xq0 = nxq0; xq1 = nxq1;
    }
    #pragma unroll
    for (int j = 0; j < 7; ++j) step(j);   // steps 1016..1022

    // fc: out[b][c] = h_T . fc_w[c] + fc_b[c]   (final h in hp[p])
    if (t < 128) {
        int c2 = t >> 6, j2 = t & 63;
        float pr = (float)hp[p][2 * j2] * fc_w[c2 * 128 + 2 * j2]
                 + (float)hp[p][2 * j2 + 1] * fc_w[c2 * 128 + 2 * j2 + 1];
        #pragma unroll
        for (int off = 32; off > 0; off >>= 1) pr += __shfl_down(pr, off, 64);
        if (j2 == 0) out[b * 2 + c2] = pr + fc_b[c2];
    }
}

// ============================ launcher ============================
extern "C" void kernel_launch(void* const* d_in, const int* in_sizes, int n_in,
                              void* d_out, int out_size, void* d_ws, size_t ws_size,
                              hipStream_t stream) {
    const int*   x      = (const int*)d_in[0];
    const float* emb    = (const float*)d_in[1];
    const float* conv_w = (const float*)d_in[2];
    const float* conv_b = (const float*)d_in[3];
    const float* w_ih   = (const float*)d_in[4];
    const float* w_hh   = (const float*)d_in[5];
    const float* b_ih   = (const float*)d_in[6];
    const float* b_hh   = (const float*)d_in[7];
    const float* fc_w   = (const float*)d_in[8];
    const float* fc_b   = (const float*)d_in[9];
    float* out = (float*)d_out;

    char* ws = (char*)d_ws;
    bf16* bt     = (bf16*)(ws + WS_BT);
    bf16* w_ihb  = (bf16*)(ws + WS_WIHB);
    bf16* pooled = (bf16*)(ws + WS_POOLED);
    bf16* embb   = (bf16*)(ws + WS_EMB);
    f16*  xg     = (f16*)(ws + WS_XG);   // overlaps embb (emb dead after conv_pool)

    emb_cvt_k<<<2500, 256, 0, stream>>>(emb, embb);
    prep_small_k<<<288, 256, 0, stream>>>(conv_w, bt, w_ih, w_ihb);
    conv_pool_k<<<2048, 256, 0, stream>>>(x, embb, bt, conv_b, pooled);
    xg_gemm_k<<<256, 256, 0, stream>>>(pooled, w_ihb, b_ih, b_hh, xg);
    lstm_fc_k<<<64, 512, 0, stream>>>(xg, w_hh, fc_w, fc_b, out);
}

// Round 2
// 640.458 us; speedup vs baseline: 1.1440x; 1.0787x over previous
//
#include <hip/hip_runtime.h>
#include <stdint.h>
#include <stddef.h>

// CNNLSTM: embed -> conv1d(K=5) -> ReLU -> maxpool4 -> LSTM(T=1023,H=128) -> fc(2)
// Inputs: x int32; all float tensors float32. Output f32.
// Internals: bf16 MFMA for conv + input-projection GEMMs; f16 MFMA recurrence.

typedef __bf16 bf16;
typedef __bf16 bf16x8 __attribute__((ext_vector_type(8)));
typedef float  f32x4  __attribute__((ext_vector_type(4)));
typedef _Float16 f16;
typedef f16 f16x2 __attribute__((ext_vector_type(2)));
typedef f16 f16x4 __attribute__((ext_vector_type(4)));
typedef f16 f16x8 __attribute__((ext_vector_type(8)));

#define MFMA16(a, b, c)  __builtin_amdgcn_mfma_f32_16x16x32_bf16((a), (b), (c), 0, 0, 0)
#define MFMA16H(a, b, c) __builtin_amdgcn_mfma_f32_16x16x32_f16((a), (b), (c), 0, 0, 0)

// Barrier draining LDS (lgkm) but NOT in-flight global prefetch loads.
#define LGKM_BARRIER() asm volatile("s_waitcnt lgkmcnt(0)\ns_barrier" ::: "memory")

// ---------------- ws layout (bytes) ----------------
#define WS_BT     0               // conv weights repacked [64][640] bf16 =    81,920
#define WS_WIHB   81920           // w_ih bf16 [512][64]                  =    65,536
#define WS_POOLED 278528          // pooled bf16 [64][1024][64]           = 8,388,608
#define WS_EMB    8667136         // emb bf16 [20000][128]                = 5,120,000
#define WS_XG     8667136         // xgc f16 [64][128][128][4][8]         = 67,108,864
// (xgc overlaps emb_bf16: emb dead after conv_pool)

// ============ prep A: emb f32 -> bf16 ============
__global__ void emb_cvt_k(const float* __restrict__ emb, bf16* __restrict__ embb) {
    int g = blockIdx.x * 256 + threadIdx.x;
    f32x4 v = *(const f32x4*)(emb + g * 4);
    bf16* d = embb + g * 4;
    d[0] = (bf16)v[0]; d[1] = (bf16)v[1]; d[2] = (bf16)v[2]; d[3] = (bf16)v[3];
}

// ============ prep B: conv_w repack->bf16; w_ih->bf16 ============
__global__ void prep_small_k(const float* __restrict__ conv_w, bf16* __restrict__ bt,
                             const float* __restrict__ w_ih, bf16* __restrict__ w_ihb) {
    int g = blockIdx.x * 256 + threadIdx.x;
    if (g < 64 * 640) {
        int f = g / 640, kk = g - f * 640;
        int k = kk >> 7, e = kk & 127;
        bt[g] = (bf16)conv_w[(f * 128 + e) * 5 + k];
    } else {
        int h = g - 64 * 640;
        if (h < 512 * 64) w_ihb[h] = (bf16)w_ih[h];
    }
}

// ============ kernel 1: embed-gather + conv + ReLU + pool4 ============
__global__ __launch_bounds__(256, 2) void conv_pool_k(
    const int* __restrict__ x, const bf16* __restrict__ embb,
    const bf16* __restrict__ bt, const float* __restrict__ conv_b,
    bf16* __restrict__ pooled)
{
    __shared__ bf16 T[144 * 136];  // 136 = 128 + 8 pad
    const int b   = blockIdx.x >> 5;
    const int l0  = (blockIdx.x & 31) << 7;
    const int tid = threadIdx.x;
    const int ln  = tid & 63, w = tid >> 6;
    const int l15 = ln & 15, quad = ln >> 4;
    const int f   = w * 16 + l15;

    bf16x8 bfrag[20];
    #pragma unroll
    for (int kc = 0; kc < 20; ++kc) {
        uint4 v = *(const uint4*)(bt + f * 640 + kc * 32 + quad * 8);
        bfrag[kc] = __builtin_bit_cast(bf16x8, v);
    }
    const float cb = conv_b[f];

    #pragma unroll
    for (int p = 0; p < 9; ++p) {
        int r = p * 16 + (tid >> 4);
        int cg = tid & 15;
        int token = l0 + r; if (token > 4095) token = 4095;
        int idx = x[b * 4096 + token];
        uint4 v = *(const uint4*)(embb + idx * 128 + cg * 8);
        *(uint4*)(&T[r * 136 + cg * 8]) = v;
    }
    __syncthreads();

    f32x4 acc[8];
    #pragma unroll
    for (int tm = 0; tm < 8; ++tm) acc[tm] = (f32x4){0.f, 0.f, 0.f, 0.f};

    #pragma unroll
    for (int kc = 0; kc < 20; ++kc) {
        const int ktap = kc >> 2;
        const int ecol = (kc & 3) * 32 + quad * 8;
        #pragma unroll
        for (int tm = 0; tm < 8; ++tm) {
            int row = tm * 16 + l15 + ktap;
            bf16x8 a = *(const bf16x8*)(&T[row * 136 + ecol]);
            acc[tm] = MFMA16(a, bfrag[kc], acc[tm]);
        }
    }

    #pragma unroll
    for (int tm = 0; tm < 8; ++tm) {
        float mx = fmaxf(fmaxf(acc[tm][0], acc[tm][1]), fmaxf(acc[tm][2], acc[tm][3]));
        mx = fmaxf(mx + cb, 0.f);
        int t = (l0 >> 2) + tm * 4 + quad;
        if (t < 1023) pooled[(b * 1024 + t) * 64 + f] = (bf16)mx;
    }
}

// ============ kernel 2: xgc = pooled @ w_ih^T + (b_ih+b_hh), chunk-layout f16 ============
// xgc[b][c][unit][gate][j], t = c*8+j. LSTM lane reads 64 contiguous B/chunk.
__global__ __launch_bounds__(256, 2) void xg_gemm_k(
    const bf16* __restrict__ pooled, const bf16* __restrict__ w_ihb,
    const float* __restrict__ b_ih, const float* __restrict__ b_hh,
    f16* __restrict__ xg)
{
    __shared__ bf16 A[256 * 72];  // 72 = 64 + 8 pad
    const int m0  = blockIdx.x * 256;
    const int tid = threadIdx.x;
    const int ln  = tid & 63, w = tid >> 6;
    const int l15 = ln & 15, quad = ln >> 4;

    #pragma unroll
    for (int i = 0; i < 8; ++i) {
        int task = i * 256 + tid;
        int row = task >> 3, ch = task & 7;
        uint4 v = *(const uint4*)(pooled + (m0 + row) * 64 + ch * 8);
        *(uint4*)(&A[row * 72 + ch * 8]) = v;
    }
    __syncthreads();

    bf16x8 afrag[4][2];
    #pragma unroll
    for (int mt = 0; mt < 4; ++mt)
        #pragma unroll
        for (int kc = 0; kc < 2; ++kc)
            afrag[mt][kc] = *(const bf16x8*)(&A[((w * 4 + mt) * 16 + l15) * 72 + kc * 32 + quad * 8]);

    const int b_idx = m0 >> 10;
    const int tbase = m0 & 1023;

    for (int nt = 0; nt < 32; ++nt) {
        const int nn = nt * 16 + l15;
        uint4 v0 = *(const uint4*)(w_ihb + nn * 64 + quad * 8);
        uint4 v1 = *(const uint4*)(w_ihb + nn * 64 + 32 + quad * 8);
        bf16x8 bf0 = __builtin_bit_cast(bf16x8, v0);
        bf16x8 bf1 = __builtin_bit_cast(bf16x8, v1);
        const float bias = b_ih[nn] + b_hh[nn];
        const int unit = nn & 127, gate = nn >> 7;
        #pragma unroll
        for (int mt = 0; mt < 4; ++mt) {
            f32x4 acc = (f32x4){0.f, 0.f, 0.f, 0.f};
            acc = MFMA16(afrag[mt][0], bf0, acc);
            acc = MFMA16(afrag[mt][1], bf1, acc);
            int t0 = tbase + (w * 4 + mt) * 16 + quad * 4;   // t0 % 4 == 0
            f16x4 sv = {(f16)(acc[0] + bias), (f16)(acc[1] + bias),
                        (f16)(acc[2] + bias), (f16)(acc[3] + bias)};
            size_t off = (((size_t)(b_idx * 128 + (t0 >> 3)) * 128 + unit) * 4 + gate) * 8 + (t0 & 7);
            *(f16x4*)(xg + off) = sv;   // 8B store, (t0&7) in {0,4}
        }
    }
}

// ============ kernel 3: LSTM recurrence (f16 MFMA) + fc head ============
// 16 WGs x 512 threads; WG bw handles batches 4*bw..4*bw+3. Per step the
// recurrence matvec is a (4x128)x(128x512) GEMM on the MATRIX pipe:
// wave w owns units w*16..w*16+15; per step 16 x mfma_f32_16x16x32_f16
// (4 gates x 4 K-chunks). A = W_hh fragments resident in VGPRs (64 regs);
// B[k][col] = h[col>>2][kc*32+k] (4 batches x 4 replicated cols) read from
// LDS (stride 144 f16 = 288B: 16B-aligned b128 reads, <=2-way bank alias).
// D: lane(quad,l15) holds rows quad*4+{0..3}, col l15 -> each lane runs ONE
// act/cell chain: unit w*16+quad*4+(l15&3) [reg picked by 3 cndmasks -- no
// runtime vector indexing], batch l15>>2. p-parity is compile-time (j&1 in
// the unrolled 8-step chunk) -> read/write bases are 2 precomputed pointers.
// R1 lesson: DOT2 on the VALU pipe put a ~500cyc/step issue floor per SIMD;
// MFMA moves the MACs to the matrix pipe (32 mfma/SIMD ~ 154cyc, overlapped
// with ~45 VALU act ops per lane per step -- m114: pipes co-schedule).
__device__ inline float sigm_(float v) {
    return __builtin_amdgcn_rcpf(1.f + __builtin_amdgcn_exp2f(-1.4426950408889634f * v));
}
__device__ inline float tanh_(float v) {
    return 1.f - 2.f * __builtin_amdgcn_rcpf(1.f + __builtin_amdgcn_exp2f(2.8853901817779268f * v));
}

__global__ __launch_bounds__(512, 2) __attribute__((amdgpu_waves_per_eu(2, 2)))
void lstm_fc_k(
    const f16* __restrict__ xgc, const float* __restrict__ w_hh,
    const float* __restrict__ fc_w, const float* __restrict__ fc_b,
    float* __restrict__ out)
{
    __shared__ __align__(16) f16 hbuf[2 * 4 * 144];   // [p][bb][144]; 288B batch stride
    __shared__ float sm[8][2];
    const int b0   = blockIdx.x << 2;
    const int t    = threadIdx.x;     // 0..511
    const int w    = t >> 6;          // wave 0..7 -> units w*16..w*16+15
    const int ln   = t & 63;
    const int l15  = ln & 15, quad = ln >> 4;
    const int bb   = l15 >> 2;        // batch sub 0..3 (D col group / B col group)
    const int c    = l15 & 3;         // which of the 4 D-rows (regs) this lane owns
    const int u    = w * 16 + quad * 4 + c;  // unit handled by this lane

    // ---- A fragments: wa[g][kc], lane holds W_hh[g*128 + w*16 + l15][kc*32 + quad*8 + j]
    f16x8 wa[4][4];
    #pragma unroll
    for (int g = 0; g < 4; ++g)
        #pragma unroll
        for (int kc = 0; kc < 4; ++kc) {
            const float* wr = w_hh + (size_t)(g * 128 + w * 16 + l15) * 128 + kc * 32 + quad * 8;
            f32x4 v0 = *(const f32x4*)(wr);
            f32x4 v1 = *(const f32x4*)(wr + 4);
            wa[g][kc] = (f16x8){(f16)v0[0], (f16)v0[1], (f16)v0[2], (f16)v0[3],
                                (f16)v1[0], (f16)v1[1], (f16)v1[2], (f16)v1[3]};
        }
    #pragma unroll
    for (int g = 0; g < 4; ++g)
        #pragma unroll
        for (int kc = 0; kc < 4; ++kc) {
            uint4 r = __builtin_bit_cast(uint4, wa[g][kc]);
            asm volatile("" : "+v"(r.x), "+v"(r.y), "+v"(r.z), "+v"(r.w));  // pin
            wa[g][kc] = __builtin_bit_cast(f16x8, r);
        }

    // xq for this lane's (batch, unit): xgc[b0+bb][ch][u][g][j]
    const f16* xb = xgc + (size_t)(b0 + bb) * 524288 + (size_t)u * 32;
    f16x8 xq0 = *(const f16x8*)(xb);
    f16x8 xq1 = *(const f16x8*)(xb + 8);
    f16x8 xq2 = *(const f16x8*)(xb + 16);
    f16x8 xq3 = *(const f16x8*)(xb + 24);
    f16x8 nx0, nx1, nx2, nx3;

    // B-frag read bases (p=0/1) and h write addrs (write hp[p^1])
    const char* rb0 = (const char*)hbuf + bb * 288 + quad * 16;
    const char* rb1 = rb0 + 1152;
    f16* wb0 = (f16*)((char*)hbuf + 1152 + bb * 288 + u * 2);  // p=0 writes hp[1]
    f16* wb1 = (f16*)((char*)hbuf +        bb * 288 + u * 2);  // p=1 writes hp[0]

    if (t < 288) ((uint32_t*)hbuf)[t] = 0u;   // zero hp[0] (1152B)
    float cst = 0.f;
    LGKM_BARRIER();

    auto step = [&](int j, int p) {
        const char* rb = p ? rb1 : rb0;
        f16x8 hb0 = *(const f16x8*)(rb);
        f16x8 hb1 = *(const f16x8*)(rb + 64);
        f16x8 hb2 = *(const f16x8*)(rb + 128);
        f16x8 hb3 = *(const f16x8*)(rb + 192);
        f32x4 a0 = (f32x4){0.f, 0.f, 0.f, 0.f};
        f32x4 a1 = a0, a2 = a0, a3 = a0;
        a0 = MFMA16H(wa[0][0], hb0, a0); a1 = MFMA16H(wa[1][0], hb0, a1);
        a2 = MFMA16H(wa[2][0], hb0, a2); a3 = MFMA16H(wa[3][0], hb0, a3);
        a0 = MFMA16H(wa[0][1], hb1, a0); a1 = MFMA16H(wa[1][1], hb1, a1);
        a2 = MFMA16H(wa[2][1], hb1, a2); a3 = MFMA16H(wa[3][1], hb1, a3);
        a0 = MFMA16H(wa[0][2], hb2, a0); a1 = MFMA16H(wa[1][2], hb2, a1);
        a2 = MFMA16H(wa[2][2], hb2, a2); a3 = MFMA16H(wa[3][2], hb2, a3);
        a0 = MFMA16H(wa[0][3], hb3, a0); a1 = MFMA16H(wa[1][3], hb3, a1);
        a2 = MFMA16H(wa[2][3], hb3, a2); a3 = MFMA16H(wa[3][3], hb3, a3);
        // reg-select (compile-time element indices; c divergent -> cndmask)
        float s0a = (c & 1) ? a0[1] : a0[0], s0b = (c & 1) ? a0[3] : a0[2];
        float s1a = (c & 1) ? a1[1] : a1[0], s1b = (c & 1) ? a1[3] : a1[2];
        float s2a = (c & 1) ? a2[1] : a2[0], s2b = (c & 1) ? a2[3] : a2[2];
        float s3a = (c & 1) ? a3[1] : a3[0], s3b = (c & 1) ? a3[3] : a3[2];
        float p0 = (c & 2) ? s0b : s0a;
        float p1 = (c & 2) ? s1b : s1a;
        float p2 = (c & 2) ? s2b : s2a;
        float p3 = (c & 2) ? s3b : s3a;
        float ig = sigm_(p0 + (float)xq0[j]);
        float fg = sigm_(p1 + (float)xq1[j]);
        float gg = tanh_(p2 + (float)xq2[j]);
        float og = sigm_(p3 + (float)xq3[j]);
        cst = fg * cst + ig * gg;
        float hn = og * tanh_(cst);
        *(p ? wb1 : wb0) = (f16)hn;
        LGKM_BARRIER();
    };

    for (int ch = 0; ch < 127; ++ch) {
        // prefetch next chunk (vmcnt: not drained by the lgkm barrier)
        const f16* nb = xb + (size_t)(ch + 1) * 4096;
        nx0 = *(const f16x8*)(nb);
        nx1 = *(const f16x8*)(nb + 8);
        nx2 = *(const f16x8*)(nb + 16);
        nx3 = *(const f16x8*)(nb + 24);
        #pragma unroll
        for (int j = 0; j < 8; ++j) step(j, j & 1);
        xq0 = nx0; xq1 = nx1; xq2 = nx2; xq3 = nx3;
    }
    #pragma unroll
    for (int j = 0; j < 7; ++j) step(j, j & 1);   // steps 1016..1022; final h -> hp[1]

    // fc: out[b0+bbf][c2] = h_T . fc_w[c2] + fc_b[c2]   (h_T in hbuf[1])
    {
        int bbf = w >> 1, uhalf = w & 1;
        int uu = uhalf * 64 + ln;
        float hv = (float)*(const f16*)((const char*)hbuf + 1152 + bbf * 288 + uu * 2);
        float pr0 = hv * fc_w[uu];
        float pr1 = hv * fc_w[128 + uu];
        #pragma unroll
        for (int off = 32; off > 0; off >>= 1) {
            pr0 += __shfl_down(pr0, off, 64);
            pr1 += __shfl_down(pr1, off, 64);
        }
        if (ln == 0) { sm[w][0] = pr0; sm[w][1] = pr1; }
    }
    __syncthreads();
    if (t < 8) {
        int bbf = t >> 1, c2 = t & 1;
        out[(b0 + bbf) * 2 + c2] = sm[bbf * 2][c2] + sm[bbf * 2 + 1][c2] + fc_b[c2];
    }
}

// ============================ launcher ============================
extern "C" void kernel_launch(void* const* d_in, const int* in_sizes, int n_in,
                              void* d_out, int out_size, void* d_ws, size_t ws_size,
                              hipStream_t stream) {
    const int*   x      = (const int*)d_in[0];
    const float* emb    = (const float*)d_in[1];
    const float* conv_w = (const float*)d_in[2];
    const float* conv_b = (const float*)d_in[3];
    const float* w_ih   = (const float*)d_in[4];
    const float* w_hh   = (const float*)d_in[5];
    const float* b_ih   = (const float*)d_in[6];
    const float* b_hh   = (const float*)d_in[7];
    const float* fc_w   = (const float*)d_in[8];
    const float* fc_b   = (const float*)d_in[9];
    float* out = (float*)d_out;

    char* ws = (char*)d_ws;
    bf16* bt     = (bf16*)(ws + WS_BT);
    bf16* w_ihb  = (bf16*)(ws + WS_WIHB);
    bf16* pooled = (bf16*)(ws + WS_POOLED);
    bf16* embb   = (bf16*)(ws + WS_EMB);
    f16*  xg     = (f16*)(ws + WS_XG);   // overlaps embb (emb dead after conv_pool)

    emb_cvt_k<<<2500, 256, 0, stream>>>(emb, embb);
    prep_small_k<<<288, 256, 0, stream>>>(conv_w, bt, w_ih, w_ihb);
    conv_pool_k<<<2048, 256, 0, stream>>>(x, embb, bt, conv_b, pooled);
    xg_gemm_k<<<256, 256, 0, stream>>>(pooled, w_ihb, b_ih, b_hh, xg);
    lstm_fc_k<<<16, 512, 0, stream>>>(xg, w_hh, fc_w, fc_b, out);
}